// Round 2
// baseline (361.896 us; speedup 1.0000x reference)
//
#include <hip/hip_runtime.h>

#define N_ATOMS 30000
#define NJ 12
#define KDIM 32
#define FDIM 128

typedef __attribute__((ext_vector_type(8))) short short8;
typedef __attribute__((ext_vector_type(4))) float f32x4;

// ws layout (bytes)
#define WFRAG_OFF 0          // 8 mats * 32768 B  (bf16 frag-linear)
#define GFRAG_OFF 262144     // 3 mats * 8192  B
#define MFRAG_OFF 286720     // 2 mats * 32768 B
#define MTMP_OFF  352256     // 2 mats * 65536 B  (f32 M_p, M_d)
#define FEA_OFF   483328     // 3 * 30000*128 bf16 (s,p,d fea)
#define FEA_ELEMS 3840000    // elements per group
#define CFEA_OFF  23523328   // 30000*128 f32 (final_c)

__device__ __forceinline__ unsigned short f2b(float f){
  unsigned u = __builtin_bit_cast(unsigned, f);
  u = (u + 0x7fffu + ((u >> 16) & 1u)) >> 16;
  return (unsigned short)u;
}
__device__ __forceinline__ float b2f(unsigned short s){
  unsigned u = ((unsigned)s) << 16;
  return __builtin_bit_cast(float, u);
}
__device__ __forceinline__ float silu_f(float x){ return x / (1.0f + __expf(-x)); }

struct Ptr8 { const float* p[8]; };
struct Ptr3 { const float* p[3]; };
struct Bias { const float* br[4]; const float* b1[4]; };

// ---------------- kernel 0a: M = P1*P2^T / D1*D2^T, plus W/G fragment packing --
__global__ __launch_bounds__(256) void k_prep(
    const float* __restrict__ P1, const float* __restrict__ P2,
    const float* __restrict__ D1, const float* __restrict__ D2,
    Ptr8 w8, Ptr3 g3, char* __restrict__ ws)
{
  int b = blockIdx.x, t = threadIdx.x;
  if (b < 16){                       // M compute: 2 mats x 8 rowblocks
    int mat = b >> 3, rb = b & 7;
    const float* A = mat ? D1 : P1;
    const float* B = mat ? D2 : P2;
    float* MT = (float*)(ws + MTMP_OFF) + (size_t)mat*16384;
    for (int it = 0; it < 8; ++it){
      int o = it*256 + t;
      int row = rb*16 + (o >> 7), col = o & 127;
      const float4* ar = (const float4*)(A + (size_t)row*128);
      const float4* br = (const float4*)(B + (size_t)col*128);
      float s = 0.f;
      #pragma unroll 8
      for (int q = 0; q < 32; ++q){
        float4 a = ar[q], c = br[q];
        s += a.x*c.x + a.y*c.y + a.z*c.z + a.w*c.w;
      }
      MT[(size_t)row*128 + col] = s;
    }
  } else if (b < 24){                // W fragment pack: 8 mats
    int mat = b - 16;
    const float* W = w8.p[mat];
    unsigned short* dst = (unsigned short*)(ws + WFRAG_OFF) + (size_t)mat*16384;
    for (int it = 0; it < 64; ++it){
      int idx = it*256 + t;
      int i = idx & 7, ln = (idx >> 3) & 63, ft = (idx >> 9) & 7, ks = idx >> 12;
      int f = ft*16 + (ln & 15);
      int k = ks*32 + ((ln >> 4) & 3)*8 + i;
      dst[idx] = f2b(W[(size_t)f*128 + k]);
    }
  } else {                           // G fragment pack: 3 mats (K=32)
    int mat = b - 24;
    const float* G = g3.p[mat];
    unsigned short* dst = (unsigned short*)(ws + GFRAG_OFF) + (size_t)mat*4096;
    for (int it = 0; it < 16; ++it){
      int idx = it*256 + t;
      int i = idx & 7, ln = (idx >> 3) & 63, ft = idx >> 9;
      int f = ft*16 + (ln & 15);
      int k = ((ln >> 4) & 3)*8 + i;
      dst[idx] = f2b(G[(size_t)f*32 + k]);
    }
  }
}

// ---------------- kernel 0b: fragment-pack M_p / M_d ---------------------------
__global__ __launch_bounds__(256) void k_mfrag(char* __restrict__ ws)
{
  int mat = blockIdx.x, t = threadIdx.x;
  const float* MT = (const float*)(ws + MTMP_OFF) + (size_t)mat*16384;
  unsigned short* dst = (unsigned short*)(ws + MFRAG_OFF) + (size_t)mat*16384;
  for (int it = 0; it < 64; ++it){
    int idx = it*256 + t;
    int i = idx & 7, ln = (idx >> 3) & 63, ft = (idx >> 9) & 7, ks = idx >> 12;
    int fp = ft*16 + (ln & 15);
    int k = ks*32 + ((ln >> 4) & 3)*8 + i;
    dst[idx] = f2b(MT[(size_t)k*128 + fp]);   // B[k][f'] = M[k][f']
  }
}

// ---------------- kernel 1: 4x ResMLP (c -> cfea f32, s/p/d -> bf16 fea) -------
__global__ __launch_bounds__(256) void k_resmlp(
    const float* __restrict__ x, char* __restrict__ ws, Bias bs)
{
  __shared__ alignas(16) char sm[32768];
  int tid = threadIdx.x, lane = tid & 63, wid = tid >> 6;
  int lo = lane & 15, hi = lane >> 4;
  int ch = blockIdx.y;
  int rowbase = blockIdx.x*64 + wid*16;
  char* xL = sm + wid*8192;
  char* hL = xL + 4096;

  // stage silu(x) frag-linear
  #pragma unroll
  for (int it = 0; it < 8; ++it){
    int e4 = it*64 + lane;
    int row = e4 >> 5, k0 = (e4 & 31)*4;
    int grow = rowbase + row; if (grow >= N_ATOMS) grow = N_ATOMS-1;
    float4 v = *(const float4*)(x + (size_t)grow*FDIM + k0);
    unsigned p0 = (unsigned)f2b(silu_f(v.x)) | ((unsigned)f2b(silu_f(v.y)) << 16);
    unsigned p1 = (unsigned)f2b(silu_f(v.z)) | ((unsigned)f2b(silu_f(v.w)) << 16);
    int ks = k0 >> 5, h2 = (k0 >> 3) & 3, i0 = k0 & 7, lanep = row | (h2 << 4);
    uint2 u; u.x = p0; u.y = p1;
    *(uint2*)(xL + ks*1024 + lanep*16 + i0*2) = u;
  }
  __syncthreads();
  short8 A[4];
  #pragma unroll
  for (int ks = 0; ks < 4; ++ks) A[ks] = *(const short8*)(xL + ks*1024 + lane*16);

  f32x4 acc[8];
  #pragma unroll
  for (int ft = 0; ft < 8; ++ft) acc[ft] = (f32x4){0,0,0,0};
  const char* wr = ws + (size_t)(ch*2)*32768;
  #pragma unroll
  for (int ks = 0; ks < 4; ++ks){
    #pragma unroll
    for (int ft = 0; ft < 8; ++ft){
      short8 B = *(const short8*)(wr + (size_t)((ks*8 + ft)*64 + lane)*16);
      acc[ft] = __builtin_amdgcn_mfma_f32_16x16x32_bf16(A[ks], B, acc[ft], 0, 0, 0);
    }
  }
  // epilogue 1: h = x + silu(x)@wr^T + br ; stage silu(h)
  const float* brp = bs.br[ch];
  #pragma unroll
  for (int ft = 0; ft < 8; ++ft){
    int f = ft*16 + lo;
    float bias = brp[f];
    #pragma unroll
    for (int r = 0; r < 4; ++r){
      int row = hi*4 + r;
      int grow = rowbase + row; if (grow >= N_ATOMS) grow = N_ATOMS-1;
      float h = acc[ft][r] + x[(size_t)grow*FDIM + f] + bias;
      float sh = silu_f(h);
      int ks2 = f >> 5, h2 = (f >> 3) & 3, i2 = f & 7, lanep = row | (h2 << 4);
      *(unsigned short*)(hL + ks2*1024 + lanep*16 + i2*2) = f2b(sh);
    }
  }
  __syncthreads();
  short8 A2[4];
  #pragma unroll
  for (int ks = 0; ks < 4; ++ks) A2[ks] = *(const short8*)(hL + ks*1024 + lane*16);

  f32x4 acc2[8];
  #pragma unroll
  for (int ft = 0; ft < 8; ++ft) acc2[ft] = (f32x4){0,0,0,0};
  const char* w1 = ws + (size_t)(ch*2 + 1)*32768;
  #pragma unroll
  for (int ks = 0; ks < 4; ++ks){
    #pragma unroll
    for (int ft = 0; ft < 8; ++ft){
      short8 B = *(const short8*)(w1 + (size_t)((ks*8 + ft)*64 + lane)*16);
      acc2[ft] = __builtin_amdgcn_mfma_f32_16x16x32_bf16(A2[ks], B, acc2[ft], 0, 0, 0);
    }
  }
  const float* b1p = bs.b1[ch];
  unsigned short* fea = (unsigned short*)(ws + FEA_OFF + (size_t)(ch > 0 ? ch-1 : 0)*7680000);
  float* cfea = (float*)(ws + CFEA_OFF);
  #pragma unroll
  for (int ft = 0; ft < 8; ++ft){
    int f = ft*16 + lo;
    float bb = b1p[f];
    #pragma unroll
    for (int r = 0; r < 4; ++r){
      int row = hi*4 + r;
      int grow = rowbase + row; if (grow >= N_ATOMS) grow = N_ATOMS-1;
      float val = acc2[ft][r] + bb;
      if (ch == 0) cfea[(size_t)grow*FDIM + f] = val;   // dup rows: identical writes
      else fea[(size_t)grow*FDIM + f] = f2b(val);
    }
  }
}

// ---------------- kernel 2 helpers ---------------------------------------------
template<int G>
__device__ __forceinline__ void do_group(
    int atom, int lane, int lo, int hi,
    const float* __restrict__ gsrc, const int* __restrict__ nbr,
    const unsigned short* __restrict__ feaG, const char* __restrict__ gfrag,
    char* gBuf, char* feaL, char* accB, float& outv0, float& outv1)
{
  constexpr int NA  = (G == 0) ? 1 : ((G == 1) ? 3 : 5);
  constexpr int NF2 = (G == 0) ? 192 : ((G == 1) ? 576 : 960);
  f32x4 z4 = {0,0,0,0};
  __syncthreads();   // WAR: prior phase's LDS reads complete before overwrite
  // zero-fill tiles (j>=12 rows must stay zero)
  #pragma unroll
  for (int t = 0; t < NA; ++t) *(f32x4*)(gBuf + t*1024 + lane*16) = z4;
  // stage g transposed into frag-linear bf16
  #pragma unroll
  for (int it = 0; it < NF2/64; ++it){
    int e2 = it*64 + lane;
    float2 v = ((const float2*)gsrc)[e2];
    #pragma unroll
    for (int q = 0; q < 2; ++q){
      int ee = 2*e2 + q;
      float val = q ? v.y : v.x;
      int j, k, a;
      if (G == 0){ j = ee >> 5; k = ee & 31; a = 0; }
      else if (G == 1){ j = ee/96; int r = ee - j*96; k = r/3; a = r - k*3; }
      else { j = ee/160; int r = ee - j*160; k = r/5; a = r - k*5; }
      *(unsigned short*)(gBuf + a*1024 + (j | ((k >> 3) << 4))*16 + (k & 7)*2) = f2b(val);
    }
  }
  // gather neighbor fea rows (bf16), 12 rows
  {
    unsigned uu[NJ];
    #pragma unroll
    for (int j = 0; j < NJ; ++j){
      int nj = nbr[atom*NJ + j];
      uu[j] = *(const unsigned*)(feaG + (size_t)nj*FDIM + lane*2);
    }
    #pragma unroll
    for (int j = 0; j < NJ; ++j)
      *(unsigned*)(feaL + j*264 + lane*4) = uu[j];
  }
  __syncthreads();   // RAW: staging visible to all lanes
  short8 Af[NA];
  #pragma unroll
  for (int a = 0; a < NA; ++a) Af[a] = *(const short8*)(gBuf + a*1024 + lane*16);
  short8 Bg[8];
  #pragma unroll
  for (int ft = 0; ft < 8; ++ft)
    Bg[ft] = *(const short8*)(gfrag + (size_t)((G*8 + ft)*64 + lane)*16);

  #pragma unroll
  for (int ft = 0; ft < 8; ++ft){
    float w0 = 0.f, w1 = 0.f, w2 = 0.f, w3 = 0.f;
    if (hi < 3){   // j = hi*4+r in [0,12)
      w0 = b2f(*(const unsigned short*)(feaL + (hi*4 + 0)*264 + (ft*16 + lo)*2));
      w1 = b2f(*(const unsigned short*)(feaL + (hi*4 + 1)*264 + (ft*16 + lo)*2));
      w2 = b2f(*(const unsigned short*)(feaL + (hi*4 + 2)*264 + (ft*16 + lo)*2));
      w3 = b2f(*(const unsigned short*)(feaL + (hi*4 + 3)*264 + (ft*16 + lo)*2));
    }
    #pragma unroll
    for (int a = 0; a < NA; ++a){
      // D[j, f] = sum_k g[j,k,a] * G[f,k]
      f32x4 c = __builtin_amdgcn_mfma_f32_16x16x32_bf16(Af[a], Bg[ft], z4, 0, 0, 0);
      float p = c[0]*w0 + c[1]*w1 + c[2]*w2 + c[3]*w3;
      p += __shfl_xor(p, 16);
      p += __shfl_xor(p, 32);          // every lane: S(f = ft*16+lo)
      if (G == 0){
        if (ft == hi)     outv0 += p;  // f = lane
        if (ft == hi + 4) outv1 += p;  // f = 64 + lane
      } else {
        if (lane < 16) *(float*)(accB + (a*132 + ft*16 + lo)*4) = p;
      }
    }
  }
}

__device__ __forceinline__ float do_quad(int lane, int lo, int hi,
    const char* __restrict__ mfragM, const char* accB)
{
  __syncthreads();   // RAW: accB writes visible
  short8 Aq[4];
  #pragma unroll
  for (int ks = 0; ks < 4; ++ks){
    short8 aa = (short8){0,0,0,0,0,0,0,0};
    if (lo < 8){
      f32x4 v0 = *(const f32x4*)(accB + (lo*132 + ks*32 + hi*8)*4);
      f32x4 v1 = *(const f32x4*)(accB + (lo*132 + ks*32 + hi*8 + 4)*4);
      aa[0] = (short)f2b(v0[0]); aa[1] = (short)f2b(v0[1]);
      aa[2] = (short)f2b(v0[2]); aa[3] = (short)f2b(v0[3]);
      aa[4] = (short)f2b(v1[0]); aa[5] = (short)f2b(v1[1]);
      aa[6] = (short)f2b(v1[2]); aa[7] = (short)f2b(v1[3]);
    }
    Aq[ks] = aa;
  }
  f32x4 acc2[8];
  #pragma unroll
  for (int ft = 0; ft < 8; ++ft) acc2[ft] = (f32x4){0,0,0,0};
  #pragma unroll
  for (int ks = 0; ks < 4; ++ks){
    #pragma unroll
    for (int ft = 0; ft < 8; ++ft){
      short8 B = *(const short8*)(mfragM + (size_t)((ks*8 + ft)*64 + lane)*16);
      acc2[ft] = __builtin_amdgcn_mfma_f32_16x16x32_bf16(Aq[ks], B, acc2[ft], 0, 0, 0);
    }
  }
  float sc = 0.f;
  #pragma unroll
  for (int ft = 0; ft < 8; ++ft){
    if (hi < 2){
      #pragma unroll
      for (int r = 0; r < 4; ++r){
        int row = hi*4 + r;
        sc += acc2[ft][r] * *(const float*)(accB + (row*132 + ft*16 + lo)*4);
      }
    }
  }
  #pragma unroll
  for (int m = 1; m < 64; m <<= 1) sc += __shfl_xor(sc, m);
  return sc;
}

// ---------------- kernel 2: env + weighted j-sum + quadratic heads -------------
__global__ __launch_bounds__(256) void k_main(
    const float* __restrict__ gs, const float* __restrict__ gp,
    const float* __restrict__ gd, const int* __restrict__ nbr,
    char* __restrict__ ws, float* __restrict__ out)
{
  __shared__ alignas(16) char sm[4*12544];
  int tid = threadIdx.x, lane = tid & 63, wid = tid >> 6;
  int lo = lane & 15, hi = lane >> 4;
  int atom = blockIdx.x*4 + wid;
  char* gBuf = sm + wid*12544;   // 5 tiles * 1024 B
  char* feaL = gBuf + 5120;      // 12 * 264 B
  char* accB = gBuf + 8288;      // 264 * 16 B zeroed (8 rows * 132 f32 used)
  const char* gfrag = ws + GFRAG_OFF;
  const char* mfrag = ws + MFRAG_OFF;
  const unsigned short* feaBase = (const unsigned short*)(ws + FEA_OFF);
  const float* cfea = (const float*)(ws + CFEA_OFF);

  f32x4 z4 = {0,0,0,0};
  #pragma unroll
  for (int it = 0; it < 5; ++it){
    int idx = it*64 + lane;
    if (idx < 264) *(f32x4*)(accB + idx*16) = z4;
  }
  float outv0 = 0.f, outv1 = 0.f;
  do_group<0>(atom, lane, lo, hi, gs + (size_t)atom*384,  nbr, feaBase,               gfrag, gBuf, feaL, accB, outv0, outv1);
  do_group<1>(atom, lane, lo, hi, gp + (size_t)atom*1152, nbr, feaBase + FEA_ELEMS,   gfrag, gBuf, feaL, accB, outv0, outv1);
  float qp = do_quad(lane, lo, hi, mfrag, accB);
  do_group<2>(atom, lane, lo, hi, gd + (size_t)atom*1920, nbr, feaBase + 2*FEA_ELEMS, gfrag, gBuf, feaL, accB, outv0, outv1);
  float qd = do_quad(lane, lo, hi, mfrag + 32768, accB);

  size_t ob = (size_t)atom*FDIM;
  float add = qp + qd;
  out[ob + lane]      = cfea[ob + lane]      + outv0 + add;   // pure write
  out[ob + 64 + lane] = cfea[ob + 64 + lane] + outv1 + add;
}

// ---------------- launch -------------------------------------------------------
extern "C" void kernel_launch(void* const* d_in, const int* in_sizes, int n_in,
                              void* d_out, int out_size, void* d_ws, size_t ws_size,
                              hipStream_t stream)
{
  const float* atom_fea = (const float*)d_in[0];
  const int*   nbr      = (const int*)d_in[1];
  const float* gs = (const float*)d_in[2];
  const float* gp = (const float*)d_in[3];
  const float* gd = (const float*)d_in[4];
  const float* Gs = (const float*)d_in[5];
  const float* Gp = (const float*)d_in[6];
  const float* Gd = (const float*)d_in[7];
  const float* P1 = (const float*)d_in[8];
  const float* P2 = (const float*)d_in[9];
  const float* D1 = (const float*)d_in[10];
  const float* D2 = (const float*)d_in[11];

  Ptr8 w8;
  w8.p[0] = (const float*)d_in[12];  // c_wr
  w8.p[1] = (const float*)d_in[14];  // c_w1
  w8.p[2] = (const float*)d_in[16];  // s_wr
  w8.p[3] = (const float*)d_in[18];  // s_w1
  w8.p[4] = (const float*)d_in[20];  // p_wr
  w8.p[5] = (const float*)d_in[22];  // p_w1
  w8.p[6] = (const float*)d_in[24];  // d_wr
  w8.p[7] = (const float*)d_in[26];  // d_w1
  Ptr3 g3; g3.p[0] = Gs; g3.p[1] = Gp; g3.p[2] = Gd;
  Bias bs;
  bs.br[0] = (const float*)d_in[13]; bs.b1[0] = (const float*)d_in[15];
  bs.br[1] = (const float*)d_in[17]; bs.b1[1] = (const float*)d_in[19];
  bs.br[2] = (const float*)d_in[21]; bs.b1[2] = (const float*)d_in[23];
  bs.br[3] = (const float*)d_in[25]; bs.b1[3] = (const float*)d_in[27];

  char* ws = (char*)d_ws;
  float* out = (float*)d_out;

  k_prep <<<27, 256, 0, stream>>>(P1, P2, D1, D2, w8, g3, ws);
  k_mfrag<<<2, 256, 0, stream>>>(ws);
  dim3 g1((N_ATOMS + 63)/64, 4);
  k_resmlp<<<g1, 256, 0, stream>>>(atom_fea, ws, bs);
  k_main <<<N_ATOMS/4, 256, 0, stream>>>(gs, gp, gd, nbr, ws, out);
}